// Round 4
// baseline (790.971 us; speedup 1.0000x reference)
//
#include <hip/hip_runtime.h>
#include <hip/hip_bf16.h>

// MoE expert MLP, grouped-GEMM formulation.
// r4: fused one-shot fp32->bf16 conversion of x/w1/w2 into separate buffers
//     (fallback to r3 chunked path if ws too small), gemm2 K-split z=2 for
//     grid size (tail fix: 1088 -> 2176 blocks), bf16 pair-output Yp with
//     topk weight applied in gemm2 epilogue (halves Yp traffic).

#define SS 8192
#define HD 1024
#define FD 4096
#define NE 8
#define TK 2
#define NP (SS * TK)
#define MAX_TILES (NP / 128 + NE)

typedef __bf16 bf16x8 __attribute__((ext_vector_type(8)));
typedef unsigned short us8 __attribute__((ext_vector_type(8)));
typedef float f32x4 __attribute__((ext_vector_type(4)));
typedef unsigned int u32;

static __device__ __forceinline__ unsigned short f2bf(float f) {
  union { float f; unsigned u; } v; v.f = f;
  return (unsigned short)((v.u + 0x7fffu + ((v.u >> 16) & 1u)) >> 16);  // RNE
}

static __device__ __forceinline__ float bf2f(unsigned short b) {
  union { unsigned u; float f; } v; v.u = ((unsigned)b) << 16;
  return v.f;
}

static __device__ __forceinline__ bf16x8 frag_ld(const unsigned short* p) {
  union { us8 u; bf16x8 b; } v;
  v.u = *(const us8*)p;
  return v.b;
}

static __device__ __forceinline__ void gll16(const void* g, void* l) {
  __builtin_amdgcn_global_load_lds(
      (const __attribute__((address_space(1))) u32*)g,
      (__attribute__((address_space(3))) u32*)l, 16, 0, 0);
}

static __device__ __forceinline__ float silu(float v) {
  return v / (1.f + __expf(-v));
}

// sigma: B-row permutation within each 64-row half: sigma(h*64+16q+l) = h*64+4l+q
static __device__ __forceinline__ int sigma(int r) {
  return (r & 64) + ((r & 15) * 4) + ((r >> 4) & 3);
}

// ---------------- bucket building ----------------

__global__ void count_kernel(const int* __restrict__ topk_e, int* __restrict__ counts) {
  __shared__ int lc[NE];
  int tid = threadIdx.x;
  if (tid < NE) lc[tid] = 0;
  __syncthreads();
  atomicAdd(&lc[topk_e[blockIdx.x * 256 + tid]], 1);
  __syncthreads();
  if (tid < NE) atomicAdd(&counts[tid], lc[tid]);
}

__global__ void plan_kernel(const int* __restrict__ counts, int* __restrict__ offsets,
                            int* __restrict__ cursors, int* __restrict__ tile_expert,
                            int* __restrict__ tile_rowstart, int* __restrict__ total_tiles) {
  if (threadIdx.x != 0 || blockIdx.x != 0) return;
  int off = 0, tt = 0;
  for (int e = 0; e < NE; ++e) {
    offsets[e] = off;
    cursors[e] = off;
    int n = counts[e];
    int nt = (n + 127) >> 7;
    for (int i = 0; i < nt; ++i) {
      tile_expert[tt] = e;
      tile_rowstart[tt] = off + i * 128;
      ++tt;
    }
    off += n;
  }
  offsets[NE] = off;
  *total_tiles = tt;
}

__global__ void scatter_kernel(const int* __restrict__ topk_e, const float* __restrict__ topk_w,
                               int* __restrict__ cursors, int* __restrict__ row_token,
                               int* __restrict__ inv, float* __restrict__ row_w) {
  __shared__ int lcnt[NE];
  __shared__ int lbase[NE];
  int tid = threadIdx.x;
  if (tid < NE) lcnt[tid] = 0;
  __syncthreads();
  int t = blockIdx.x * 256 + tid;
  int e = topk_e[t];
  int my = atomicAdd(&lcnt[e], 1);
  __syncthreads();
  if (tid < NE) lbase[tid] = atomicAdd(&cursors[tid], lcnt[tid]);
  __syncthreads();
  int pos = lbase[e] + my;
  row_token[pos] = t / TK;
  row_w[pos] = topk_w[t];
  inv[t] = pos;
}

// ---------------- fp32 -> bf16 converts ----------------

// Path A: one streaming kernel for x, w1, w2 (flat copies, FC == FD).
#define XN ((size_t)SS * HD)
#define W1N ((size_t)NE * FD * HD)

__global__ void conv_all_kernel(const float* __restrict__ x, const float* __restrict__ w1,
                                const float* __restrict__ w2,
                                unsigned short* __restrict__ xb, unsigned short* __restrict__ w1c,
                                unsigned short* __restrict__ w2c) {
  size_t i = ((size_t)blockIdx.x * 256 + threadIdx.x) * 8;
  const float* src;
  unsigned short* dst;
  size_t off;
  if (i < XN) { src = x; dst = xb; off = i; }
  else if (i < XN + W1N) { src = w1; dst = w1c; off = i - XN; }
  else { src = w2; dst = w2c; off = i - XN - W1N; }
  float4 a = *(const float4*)(src + off);
  float4 b = *(const float4*)(src + off + 4);
  us8 o = {f2bf(a.x), f2bf(a.y), f2bf(a.z), f2bf(a.w),
           f2bf(b.x), f2bf(b.y), f2bf(b.z), f2bf(b.w)};
  *(us8*)(dst + off) = o;
}

// Path B (fallback): chunked converts (shared weight scratch), as r3.
__global__ void conv_x_kernel(const float* __restrict__ x, unsigned short* __restrict__ xb) {
  int i = blockIdx.x * 256 + threadIdx.x;
  const float4* s = (const float4*)(x + (size_t)i * 8);
  float4 a = s[0], b = s[1];
  us8 o = {f2bf(a.x), f2bf(a.y), f2bf(a.z), f2bf(a.w),
           f2bf(b.x), f2bf(b.y), f2bf(b.z), f2bf(b.w)};
  *(us8*)(xb + (size_t)i * 8) = o;
}

__global__ void conv_w1c_kernel(const float* __restrict__ w1, unsigned short* __restrict__ wc,
                                int c, int FC) {
  int i = blockIdx.x * 256 + threadIdx.x;
  int per_e = FC * HD;
  int pos = i * 8;
  int e = pos / per_e;
  int rem = pos - e * per_e;
  const float4* s = (const float4*)(w1 + ((size_t)e * FD + (size_t)c * FC) * HD + rem);
  float4 a = s[0], b = s[1];
  us8 o = {f2bf(a.x), f2bf(a.y), f2bf(a.z), f2bf(a.w),
           f2bf(b.x), f2bf(b.y), f2bf(b.z), f2bf(b.w)};
  *(us8*)(wc + (size_t)pos) = o;
}

__global__ void conv_w2c_kernel(const float* __restrict__ w2, unsigned short* __restrict__ wc,
                                int c, int FC) {
  int i = blockIdx.x * 256 + threadIdx.x;
  int per_e = HD * FC;
  int pos = i * 8;
  int e = pos / per_e;
  int rem = pos - e * per_e;
  int h = rem / FC;
  int f0 = rem - h * FC;
  const float4* s = (const float4*)(w2 + ((size_t)e * HD + h) * FD + (size_t)c * FC + f0);
  float4 a = s[0], b = s[1];
  us8 o = {f2bf(a.x), f2bf(a.y), f2bf(a.z), f2bf(a.w),
           f2bf(b.x), f2bf(b.y), f2bf(b.z), f2bf(b.w)};
  *(us8*)(wc + (size_t)pos) = o;
}

// ---------------- GEMM1: Hc = silu(Xg @ W1c^T) ----------------
// 128x128 tile, BK=64, global_load_lds staging, 8-quad XOR swizzle.

__global__ __launch_bounds__(256) void gemm1_kernel(
    const unsigned short* __restrict__ xb, const unsigned short* __restrict__ w1c,
    const int* __restrict__ row_token, const int* __restrict__ offsets,
    const int* __restrict__ tile_expert, const int* __restrict__ tile_rowstart,
    const int* __restrict__ total_tiles,
    unsigned short* __restrict__ Hbuf, int FC) {
  int rt = blockIdx.x;
  if (rt >= *total_tiles) return;
  int e = tile_expert[rt];
  int rstart = tile_rowstart[rt];
  int nvalid = offsets[e + 1] - rstart;
  if (nvalid > 128) nvalid = 128;
  int fb = blockIdx.y * 128;

  __shared__ unsigned short Asm[8192];   // 128 rows x 8 slots x 8 bf16 = 16 KB
  __shared__ unsigned short Bsm[8192];

  int tid = threadIdx.x, lane = tid & 63, wv = tid >> 6;
  int qel = ((lane & 7) ^ ((lane >> 3) & 7)) * 8;

  const unsigned short* ag[4];
  const unsigned short* bg[4];
#pragma unroll
  for (int p = 0; p < 4; ++p) {
    int r = p * 32 + wv * 8 + (lane >> 3);
    int rg = rstart + r;
    if (rg > NP - 1) rg = NP - 1;
    ag[p] = xb + (size_t)row_token[rg] * HD + qel;
    bg[p] = w1c + ((size_t)e * FC + fb + sigma(r)) * HD + qel;
  }

  f32x4 acc[4][4];
  f32x4 vz = {0.f, 0.f, 0.f, 0.f};
#pragma unroll
  for (int i = 0; i < 4; ++i)
#pragma unroll
    for (int j = 0; j < 4; ++j) acc[i][j] = vz;

  int wm = (wv & 1) * 64, wn = (wv >> 1) * 64;
  int lr = lane & 15;

  for (int kb = 0; kb < HD / 64; ++kb) {
    __syncthreads();
#pragma unroll
    for (int p = 0; p < 4; ++p) {
      gll16(ag[p], Asm + (p * 256 + wv * 64) * 8);
      gll16(bg[p], Bsm + (p * 256 + wv * 64) * 8);
      ag[p] += 64; bg[p] += 64;
    }
    __syncthreads();
#pragma unroll
    for (int t = 0; t < 2; ++t) {
      int qsl = ((t * 4 + (lane >> 4)) ^ (lr & 7)) * 8;
      bf16x8 af[4], bfr[4];
#pragma unroll
      for (int i = 0; i < 4; ++i) af[i] = frag_ld(&Asm[(wm + i * 16 + lr) * 64 + qsl]);
#pragma unroll
      for (int j = 0; j < 4; ++j) bfr[j] = frag_ld(&Bsm[(wn + j * 16 + lr) * 64 + qsl]);
#pragma unroll
      for (int i = 0; i < 4; ++i)
#pragma unroll
        for (int j = 0; j < 4; ++j)
          acc[i][j] = __builtin_amdgcn_mfma_f32_16x16x32_bf16(af[i], bfr[j], acc[i][j], 0, 0, 0);
    }
  }

  int cb = wn + (lane & 15) * 4;
  int rq = (lane >> 4) * 4;
#pragma unroll
  for (int i = 0; i < 4; ++i) {
#pragma unroll
    for (int r = 0; r < 4; ++r) {
      int row = wm + i * 16 + rq + r;
      if (row < nvalid) {
        ushort4 hv;
        hv.x = f2bf(silu(acc[i][0][r]));
        hv.y = f2bf(silu(acc[i][1][r]));
        hv.z = f2bf(silu(acc[i][2][r]));
        hv.w = f2bf(silu(acc[i][3][r]));
        *(ushort4*)&Hbuf[(size_t)(rstart + row) * FC + fb + cb] = hv;
      }
    }
  }
}

// ---------------- GEMM2 path A: Yp[z] = row_w * (Hc @ W2c^T) halves, bf16 out ----------------
// grid (tiles, HD/128, 2): z splits K; each half writes its own bf16 buffer.

__global__ __launch_bounds__(256) void gemm2a_kernel(
    const unsigned short* __restrict__ Hbuf, const unsigned short* __restrict__ w2c,
    const float* __restrict__ row_w, const int* __restrict__ offsets,
    const int* __restrict__ tile_expert, const int* __restrict__ tile_rowstart,
    const int* __restrict__ total_tiles,
    unsigned short* __restrict__ Yp) {
  int rt = blockIdx.x;
  if (rt >= *total_tiles) return;
  int e = tile_expert[rt];
  int rstart = tile_rowstart[rt];
  int nvalid = offsets[e + 1] - rstart;
  if (nvalid > 128) nvalid = 128;
  int hb = blockIdx.y * 128;
  int koff = blockIdx.z * (FD / 2);
  unsigned short* Ypz = Yp + (size_t)blockIdx.z * NP * HD;

  __shared__ unsigned short Asm[8192];
  __shared__ unsigned short Bsm[8192];

  int tid = threadIdx.x, lane = tid & 63, wv = tid >> 6;
  int qel = ((lane & 7) ^ ((lane >> 3) & 7)) * 8;

  const unsigned short* ag[4];
  const unsigned short* bg[4];
#pragma unroll
  for (int p = 0; p < 4; ++p) {
    int r = p * 32 + wv * 8 + (lane >> 3);
    int rg = rstart + r;
    if (rg > NP - 1) rg = NP - 1;
    ag[p] = Hbuf + (size_t)rg * FD + koff + qel;
    bg[p] = w2c + ((size_t)e * HD + hb + sigma(r)) * FD + koff + qel;
  }

  f32x4 acc[4][4];
  f32x4 vz = {0.f, 0.f, 0.f, 0.f};
#pragma unroll
  for (int i = 0; i < 4; ++i)
#pragma unroll
    for (int j = 0; j < 4; ++j) acc[i][j] = vz;

  int wm = (wv & 1) * 64, wn = (wv >> 1) * 64;
  int lr = lane & 15;

  for (int kb = 0; kb < (FD / 2) / 64; ++kb) {
    __syncthreads();
#pragma unroll
    for (int p = 0; p < 4; ++p) {
      gll16(ag[p], Asm + (p * 256 + wv * 64) * 8);
      gll16(bg[p], Bsm + (p * 256 + wv * 64) * 8);
      ag[p] += 64; bg[p] += 64;
    }
    __syncthreads();
#pragma unroll
    for (int t = 0; t < 2; ++t) {
      int qsl = ((t * 4 + (lane >> 4)) ^ (lr & 7)) * 8;
      bf16x8 af[4], bfr[4];
#pragma unroll
      for (int i = 0; i < 4; ++i) af[i] = frag_ld(&Asm[(wm + i * 16 + lr) * 64 + qsl]);
#pragma unroll
      for (int j = 0; j < 4; ++j) bfr[j] = frag_ld(&Bsm[(wn + j * 16 + lr) * 64 + qsl]);
#pragma unroll
      for (int i = 0; i < 4; ++i)
#pragma unroll
        for (int j = 0; j < 4; ++j)
          acc[i][j] = __builtin_amdgcn_mfma_f32_16x16x32_bf16(af[i], bfr[j], acc[i][j], 0, 0, 0);
    }
  }

  int cb = wn + (lane & 15) * 4;
  int rq = (lane >> 4) * 4;
#pragma unroll
  for (int i = 0; i < 4; ++i) {
#pragma unroll
    for (int r = 0; r < 4; ++r) {
      int row = wm + i * 16 + rq + r;
      if (row < nvalid) {
        int rg = rstart + row;
        float wgt = row_w[rg];
        ushort4 hv;
        hv.x = f2bf(wgt * acc[i][0][r]);
        hv.y = f2bf(wgt * acc[i][1][r]);
        hv.z = f2bf(wgt * acc[i][2][r]);
        hv.w = f2bf(wgt * acc[i][3][r]);
        *(ushort4*)&Ypz[(size_t)rg * HD + hb + cb] = hv;
      }
    }
  }
}

// combine A: y[s] = sum_k sum_z Yp[z][inv[2s+k]]  (weights pre-applied)
__global__ void combine_a_kernel(const unsigned short* __restrict__ Yp,
                                 const int* __restrict__ inv, float* __restrict__ y) {
  int s = blockIdx.x;
  int c = threadIdx.x * 4;
  float4 o = {0.f, 0.f, 0.f, 0.f};
#pragma unroll
  for (int k = 0; k < 2; ++k) {
    int i = inv[s * 2 + k];
#pragma unroll
    for (int z = 0; z < 2; ++z) {
      ushort4 v = *(const ushort4*)(Yp + ((size_t)z * NP + i) * HD + c);
      o.x += bf2f(v.x); o.y += bf2f(v.y); o.z += bf2f(v.z); o.w += bf2f(v.w);
    }
  }
  *(float4*)(y + (size_t)s * HD + c) = o;
}

// ---------------- GEMM2 path B (fallback, r3-proven): fp32 Yp accumulate ----------------

__global__ __launch_bounds__(256) void gemm2b_kernel(
    const unsigned short* __restrict__ Hbuf, const unsigned short* __restrict__ w2c,
    const int* __restrict__ offsets,
    const int* __restrict__ tile_expert, const int* __restrict__ tile_rowstart,
    const int* __restrict__ total_tiles,
    float* __restrict__ Yp, int FC, int first) {
  int rt = blockIdx.x;
  if (rt >= *total_tiles) return;
  int e = tile_expert[rt];
  int rstart = tile_rowstart[rt];
  int nvalid = offsets[e + 1] - rstart;
  if (nvalid > 128) nvalid = 128;
  int hb = blockIdx.y * 128;

  __shared__ unsigned short Asm[8192];
  __shared__ unsigned short Bsm[8192];

  int tid = threadIdx.x, lane = tid & 63, wv = tid >> 6;
  int qel = ((lane & 7) ^ ((lane >> 3) & 7)) * 8;

  const unsigned short* ag[4];
  const unsigned short* bg[4];
#pragma unroll
  for (int p = 0; p < 4; ++p) {
    int r = p * 32 + wv * 8 + (lane >> 3);
    int rg = rstart + r;
    if (rg > NP - 1) rg = NP - 1;
    ag[p] = Hbuf + (size_t)rg * FC + qel;
    bg[p] = w2c + ((size_t)e * HD + hb + sigma(r)) * FC + qel;
  }

  f32x4 acc[4][4];
  f32x4 vz = {0.f, 0.f, 0.f, 0.f};
#pragma unroll
  for (int i = 0; i < 4; ++i)
#pragma unroll
    for (int j = 0; j < 4; ++j) acc[i][j] = vz;

  int wm = (wv & 1) * 64, wn = (wv >> 1) * 64;
  int lr = lane & 15;

  for (int kb = 0; kb < FC / 64; ++kb) {
    __syncthreads();
#pragma unroll
    for (int p = 0; p < 4; ++p) {
      gll16(ag[p], Asm + (p * 256 + wv * 64) * 8);
      gll16(bg[p], Bsm + (p * 256 + wv * 64) * 8);
      ag[p] += 64; bg[p] += 64;
    }
    __syncthreads();
#pragma unroll
    for (int t = 0; t < 2; ++t) {
      int qsl = ((t * 4 + (lane >> 4)) ^ (lr & 7)) * 8;
      bf16x8 af[4], bfr[4];
#pragma unroll
      for (int i = 0; i < 4; ++i) af[i] = frag_ld(&Asm[(wm + i * 16 + lr) * 64 + qsl]);
#pragma unroll
      for (int j = 0; j < 4; ++j) bfr[j] = frag_ld(&Bsm[(wn + j * 16 + lr) * 64 + qsl]);
#pragma unroll
      for (int i = 0; i < 4; ++i)
#pragma unroll
        for (int j = 0; j < 4; ++j)
          acc[i][j] = __builtin_amdgcn_mfma_f32_16x16x32_bf16(af[i], bfr[j], acc[i][j], 0, 0, 0);
    }
  }

  int cb = wn + (lane & 15) * 4;
  int rq = (lane >> 4) * 4;
#pragma unroll
  for (int i = 0; i < 4; ++i) {
#pragma unroll
    for (int r = 0; r < 4; ++r) {
      int row = wm + i * 16 + rq + r;
      if (row < nvalid) {
        float* dst = Yp + (size_t)(rstart + row) * HD + hb + cb;
        float4 v;
        v.x = acc[i][0][r]; v.y = acc[i][1][r]; v.z = acc[i][2][r]; v.w = acc[i][3][r];
        if (!first) {
          float4 o = *(const float4*)dst;
          v.x += o.x; v.y += o.y; v.z += o.z; v.w += o.w;
        }
        *(float4*)dst = v;
      }
    }
  }
}

__global__ void combine_b_kernel(const float* __restrict__ Yp, const int* __restrict__ inv,
                                 const float* __restrict__ topk_w, float* __restrict__ y) {
  int s = blockIdx.x;
  int c = threadIdx.x * 4;
  int i0 = inv[s * 2], i1 = inv[s * 2 + 1];
  float w0 = topk_w[s * 2], w1 = topk_w[s * 2 + 1];
  float4 a = *(const float4*)(Yp + (size_t)i0 * HD + c);
  float4 b = *(const float4*)(Yp + (size_t)i1 * HD + c);
  float4 o;
  o.x = w0 * a.x + w1 * b.x;
  o.y = w0 * a.y + w1 * b.y;
  o.z = w0 * a.z + w1 * b.z;
  o.w = w0 * a.w + w1 * b.w;
  *(float4*)(y + (size_t)s * HD + c) = o;
}

// ---------------- host ----------------

extern "C" void kernel_launch(void* const* d_in, const int* in_sizes, int n_in,
                              void* d_out, int out_size, void* d_ws, size_t ws_size,
                              hipStream_t stream) {
  const float* x      = (const float*)d_in[0];
  const int*   topk_e = (const int*)d_in[1];
  const float* topk_w = (const float*)d_in[2];
  const float* w1     = (const float*)d_in[3];
  const float* w2     = (const float*)d_in[4];
  float* y = (float*)d_out;

  char* ws = (char*)d_ws;
  int* counts        = (int*)(ws + 0);
  int* cursors       = (int*)(ws + 64);
  int* offsets       = (int*)(ws + 128);
  int* total_tiles   = (int*)(ws + 192);
  int* tile_expert   = (int*)(ws + 256);
  int* tile_rowstart = (int*)(ws + 1024);
  int* row_token     = (int*)(ws + 4096);
  int* inv           = (int*)(ws + 4096 + (size_t)NP * 4);
  float* row_w       = (float*)(ws + 4096 + (size_t)NP * 8);
  size_t hdr = 4096 + (size_t)NP * 12;

  size_t xbytes  = (size_t)SS * HD * 2;            // 16.8 MB
  size_t w1bytes = (size_t)NE * FD * HD * 2;       // 67.1 MB
  size_t hbytes  = (size_t)NP * FD * 2;            // 134.2 MB
  size_t ypAbytes = (size_t)2 * NP * HD * 2;       // 67.1 MB (2 bf16 halves)

  unsigned short* xb = (unsigned short*)(ws + hdr);

  size_t needA = hdr + xbytes + 2 * w1bytes + hbytes + ypAbytes;   // ~352 MB

  hipMemsetAsync(d_ws, 0, 2048, stream);
  count_kernel<<<NP / 256, 256, 0, stream>>>(topk_e, counts);
  plan_kernel<<<1, 1, 0, stream>>>(counts, offsets, cursors, tile_expert, tile_rowstart, total_tiles);
  scatter_kernel<<<NP / 256, 256, 0, stream>>>(topk_e, topk_w, cursors, row_token, inv, row_w);

  if (ws_size >= needA) {
    // ---- Path A: full buffers, fused conv, z-split gemm2, bf16 Yp ----
    unsigned short* w1c  = xb + XN;
    unsigned short* w2c  = w1c + W1N;
    unsigned short* Hbuf = w2c + W1N;
    unsigned short* Yp   = Hbuf + (size_t)NP * FD;

    size_t tot8 = (XN + 2 * W1N) / 8;              // threads (each does 8 elems)
    conv_all_kernel<<<(int)(tot8 / 256), 256, 0, stream>>>(x, w1, w2, xb, w1c, w2c);

    gemm1_kernel<<<dim3(MAX_TILES, FD / 128), 256, 0, stream>>>(
        xb, w1c, row_token, offsets, tile_expert, tile_rowstart, total_tiles, Hbuf, FD);
    gemm2a_kernel<<<dim3(MAX_TILES, HD / 128, 2), 256, 0, stream>>>(
        Hbuf, w2c, row_w, offsets, tile_expert, tile_rowstart, total_tiles, Yp);
    combine_a_kernel<<<SS, 256, 0, stream>>>(Yp, inv, y);
  } else {
    // ---- Path B: r3 chunked fallback (shared weight scratch, fp32 Yp) ----
    size_t ypbytes = (size_t)NP * HD * 4;
    int FC = FD;
    while (FC > 256) {
      size_t need = hdr + xbytes + (size_t)NE * FC * HD * 2 + (size_t)NP * FC * 2 + ypbytes;
      if (need <= ws_size) break;
      FC >>= 1;
    }
    unsigned short* wc = xb + XN;
    unsigned short* Hbuf = wc + (size_t)NE * FC * HD;
    float* Yp = (float*)(Hbuf + (size_t)NP * FC);

    conv_x_kernel<<<SS * HD / 8 / 256, 256, 0, stream>>>(x, xb);
    int nchunks = FD / FC;
    int wblocks = (int)((size_t)NE * FC * HD / 8 / 256);
    for (int c = 0; c < nchunks; ++c) {
      conv_w1c_kernel<<<wblocks, 256, 0, stream>>>(w1, wc, c, FC);
      gemm1_kernel<<<dim3(MAX_TILES, FC / 128), 256, 0, stream>>>(
          xb, wc, row_token, offsets, tile_expert, tile_rowstart, total_tiles, Hbuf, FC);
      conv_w2c_kernel<<<wblocks, 256, 0, stream>>>(w2, wc, c, FC);
      gemm2b_kernel<<<dim3(MAX_TILES, HD / 128), 256, 0, stream>>>(
          Hbuf, wc, offsets, tile_expert, tile_rowstart, total_tiles, Yp, FC, c == 0 ? 1 : 0);
    }
    combine_b_kernel<<<SS, 256, 0, stream>>>(Yp, inv, topk_w, y);
  }
}

// Round 5
// 737.777 us; speedup vs baseline: 1.0721x; 1.0721x over previous
//
#include <hip/hip_runtime.h>
#include <hip/hip_bf16.h>

// MoE expert MLP, grouped-GEMM formulation.
// r5: (1) nontemporal stores for streamed outputs (Hbuf/Yp/y) so the LLC keeps
//     the GEMM operands instead of dead write data (r4 FETCH was 428 MB vs
//     ~100 MB unique -> LLC thrash); (2) 512-thread GEMM blocks, wave=32x64,
//     acc 32 AGPR + launch_bounds(512,4) to get under the 128-reg wave
//     allocation bucket (22% -> target ~44% occupancy); (3) r3's LLC-warm
//     kernel ordering (conv_w1 -> gemm1 -> conv_w2 -> gemm2).

#define SS 8192
#define HD 1024
#define FD 4096
#define NE 8
#define TK 2
#define NP (SS * TK)
#define MAX_TILES (NP / 128 + NE)

typedef __bf16 bf16x8 __attribute__((ext_vector_type(8)));
typedef unsigned short us8 __attribute__((ext_vector_type(8)));
typedef unsigned short us4 __attribute__((ext_vector_type(4)));
typedef float f32x4 __attribute__((ext_vector_type(4)));
typedef unsigned int u32;

static __device__ __forceinline__ unsigned short f2bf(float f) {
  union { float f; unsigned u; } v; v.f = f;
  return (unsigned short)((v.u + 0x7fffu + ((v.u >> 16) & 1u)) >> 16);  // RNE
}

static __device__ __forceinline__ float bf2f(unsigned short b) {
  union { unsigned u; float f; } v; v.u = ((unsigned)b) << 16;
  return v.f;
}

static __device__ __forceinline__ bf16x8 frag_ld(const unsigned short* p) {
  union { us8 u; bf16x8 b; } v;
  v.u = *(const us8*)p;
  return v.b;
}

static __device__ __forceinline__ void gll16(const void* g, void* l) {
  __builtin_amdgcn_global_load_lds(
      (const __attribute__((address_space(1))) u32*)g,
      (__attribute__((address_space(3))) u32*)l, 16, 0, 0);
}

static __device__ __forceinline__ float silu(float v) {
  return v / (1.f + __expf(-v));
}

static __device__ __forceinline__ void nt_store_us4(us4 v, unsigned short* p) {
  __builtin_nontemporal_store(v, (us4*)p);
}

static __device__ __forceinline__ void nt_store_f4(f32x4 v, float* p) {
  __builtin_nontemporal_store(v, (f32x4*)p);
}

// sigma: B-row permutation within each 64-row half: sigma(h*64+16q+l) = h*64+4l+q
static __device__ __forceinline__ int sigma(int r) {
  return (r & 64) + ((r & 15) * 4) + ((r >> 4) & 3);
}

// ---------------- bucket building ----------------

__global__ void count_kernel(const int* __restrict__ topk_e, int* __restrict__ counts) {
  __shared__ int lc[NE];
  int tid = threadIdx.x;
  if (tid < NE) lc[tid] = 0;
  __syncthreads();
  atomicAdd(&lc[topk_e[blockIdx.x * 256 + tid]], 1);
  __syncthreads();
  if (tid < NE) atomicAdd(&counts[tid], lc[tid]);
}

__global__ void plan_kernel(const int* __restrict__ counts, int* __restrict__ offsets,
                            int* __restrict__ cursors, int* __restrict__ tile_expert,
                            int* __restrict__ tile_rowstart, int* __restrict__ total_tiles) {
  if (threadIdx.x != 0 || blockIdx.x != 0) return;
  int off = 0, tt = 0;
  for (int e = 0; e < NE; ++e) {
    offsets[e] = off;
    cursors[e] = off;
    int n = counts[e];
    int nt = (n + 127) >> 7;
    for (int i = 0; i < nt; ++i) {
      tile_expert[tt] = e;
      tile_rowstart[tt] = off + i * 128;
      ++tt;
    }
    off += n;
  }
  offsets[NE] = off;
  *total_tiles = tt;
}

__global__ void scatter_kernel(const int* __restrict__ topk_e, const float* __restrict__ topk_w,
                               int* __restrict__ cursors, int* __restrict__ row_token,
                               int* __restrict__ inv, float* __restrict__ row_w) {
  __shared__ int lcnt[NE];
  __shared__ int lbase[NE];
  int tid = threadIdx.x;
  if (tid < NE) lcnt[tid] = 0;
  __syncthreads();
  int t = blockIdx.x * 256 + tid;
  int e = topk_e[t];
  int my = atomicAdd(&lcnt[e], 1);
  __syncthreads();
  if (tid < NE) lbase[tid] = atomicAdd(&cursors[tid], lcnt[tid]);
  __syncthreads();
  int pos = lbase[e] + my;
  row_token[pos] = t / TK;
  row_w[pos] = topk_w[t];
  inv[t] = pos;
}

// ---------------- fp32 -> bf16 converts ----------------

#define XN ((size_t)SS * HD)
#define W1N ((size_t)NE * FD * HD)

__global__ void conv_x_kernel(const float* __restrict__ x, unsigned short* __restrict__ xb) {
  int i = blockIdx.x * 256 + threadIdx.x;
  const float4* s = (const float4*)(x + (size_t)i * 8);
  float4 a = s[0], b = s[1];
  us8 o = {f2bf(a.x), f2bf(a.y), f2bf(a.z), f2bf(a.w),
           f2bf(b.x), f2bf(b.y), f2bf(b.z), f2bf(b.w)};
  *(us8*)(xb + (size_t)i * 8) = o;
}

__global__ void conv_w1c_kernel(const float* __restrict__ w1, unsigned short* __restrict__ wc,
                                int c, int FC) {
  int i = blockIdx.x * 256 + threadIdx.x;
  int per_e = FC * HD;
  int pos = i * 8;
  int e = pos / per_e;
  int rem = pos - e * per_e;
  const float4* s = (const float4*)(w1 + ((size_t)e * FD + (size_t)c * FC) * HD + rem);
  float4 a = s[0], b = s[1];
  us8 o = {f2bf(a.x), f2bf(a.y), f2bf(a.z), f2bf(a.w),
           f2bf(b.x), f2bf(b.y), f2bf(b.z), f2bf(b.w)};
  *(us8*)(wc + (size_t)pos) = o;
}

__global__ void conv_w2c_kernel(const float* __restrict__ w2, unsigned short* __restrict__ wc,
                                int c, int FC) {
  int i = blockIdx.x * 256 + threadIdx.x;
  int per_e = HD * FC;
  int pos = i * 8;
  int e = pos / per_e;
  int rem = pos - e * per_e;
  int h = rem / FC;
  int f0 = rem - h * FC;
  const float4* s = (const float4*)(w2 + ((size_t)e * HD + h) * FD + (size_t)c * FC + f0);
  float4 a = s[0], b = s[1];
  us8 o = {f2bf(a.x), f2bf(a.y), f2bf(a.z), f2bf(a.w),
           f2bf(b.x), f2bf(b.y), f2bf(b.z), f2bf(b.w)};
  *(us8*)(wc + (size_t)pos) = o;
}

// ---------------- GEMM1: Hc = silu(Xg @ W1c^T), 512 threads ----------------
// 128x128 tile, BK=64, 8 waves each computing 32x64; global_load_lds staging,
// 8-quad XOR swizzle (slot = row*8 + (q ^ (row&7))) -> conflict-free b128.

__global__ __launch_bounds__(512, 4) void gemm1_kernel(
    const unsigned short* __restrict__ xb, const unsigned short* __restrict__ w1c,
    const int* __restrict__ row_token, const int* __restrict__ offsets,
    const int* __restrict__ tile_expert, const int* __restrict__ tile_rowstart,
    const int* __restrict__ total_tiles,
    unsigned short* __restrict__ Hbuf, int FC) {
  int rt = blockIdx.x;
  if (rt >= *total_tiles) return;
  int e = tile_expert[rt];
  int rstart = tile_rowstart[rt];
  int nvalid = offsets[e + 1] - rstart;
  if (nvalid > 128) nvalid = 128;
  int fb = blockIdx.y * 128;

  __shared__ unsigned short Asm[8192];   // 128 rows x 8 slots x 8 bf16 = 16 KB
  __shared__ unsigned short Bsm[8192];

  int tid = threadIdx.x, lane = tid & 63, wv = tid >> 6;   // wv in 0..7
  int qel = ((lane & 7) ^ ((lane >> 3) & 7)) * 8;

  const unsigned short* ag[2];
  const unsigned short* bg[2];
#pragma unroll
  for (int p = 0; p < 2; ++p) {
    int r = p * 64 + wv * 8 + (lane >> 3);
    int rg = rstart + r;
    if (rg > NP - 1) rg = NP - 1;
    ag[p] = xb + (size_t)row_token[rg] * HD + qel;
    bg[p] = w1c + ((size_t)e * FC + fb + sigma(r)) * HD + qel;
  }

  f32x4 acc[2][4];
  f32x4 vz = {0.f, 0.f, 0.f, 0.f};
#pragma unroll
  for (int i = 0; i < 2; ++i)
#pragma unroll
    for (int j = 0; j < 4; ++j) acc[i][j] = vz;

  int wm = (wv & 3) * 32, wn = (wv >> 2) * 64;
  int lr = lane & 15;

  for (int kb = 0; kb < HD / 64; ++kb) {
    __syncthreads();
#pragma unroll
    for (int p = 0; p < 2; ++p) {
      gll16(ag[p], Asm + (p * 512 + wv * 64) * 8);
      gll16(bg[p], Bsm + (p * 512 + wv * 64) * 8);
      ag[p] += 64; bg[p] += 64;
    }
    __syncthreads();
#pragma unroll
    for (int t = 0; t < 2; ++t) {
      int qsl = ((t * 4 + (lane >> 4)) ^ (lr & 7)) * 8;
      bf16x8 af[2], bfr[4];
#pragma unroll
      for (int i = 0; i < 2; ++i) af[i] = frag_ld(&Asm[(wm + i * 16 + lr) * 64 + qsl]);
#pragma unroll
      for (int j = 0; j < 4; ++j) bfr[j] = frag_ld(&Bsm[(wn + j * 16 + lr) * 64 + qsl]);
#pragma unroll
      for (int i = 0; i < 2; ++i)
#pragma unroll
        for (int j = 0; j < 4; ++j)
          acc[i][j] = __builtin_amdgcn_mfma_f32_16x16x32_bf16(af[i], bfr[j], acc[i][j], 0, 0, 0);
    }
  }

  // epilogue: sigma'd B means lane owns 4 contiguous cols; nt stores (Hbuf is
  // re-read only after >LLC of traffic -> don't evict w1c/xb with it)
  int cb = wn + (lane & 15) * 4;
  int rq = (lane >> 4) * 4;
#pragma unroll
  for (int i = 0; i < 2; ++i) {
#pragma unroll
    for (int r = 0; r < 4; ++r) {
      int row = wm + i * 16 + rq + r;
      if (row < nvalid) {
        us4 hv = {f2bf(silu(acc[i][0][r])), f2bf(silu(acc[i][1][r])),
                  f2bf(silu(acc[i][2][r])), f2bf(silu(acc[i][3][r]))};
        nt_store_us4(hv, &Hbuf[(size_t)(rstart + row) * FC + fb + cb]);
      }
    }
  }
}

// ---------------- GEMM2: Yp[z] = row_w * (Hc @ W2c^T) halves, bf16, 512 thr ----------------

__global__ __launch_bounds__(512, 4) void gemm2a_kernel(
    const unsigned short* __restrict__ Hbuf, const unsigned short* __restrict__ w2c,
    const float* __restrict__ row_w, const int* __restrict__ offsets,
    const int* __restrict__ tile_expert, const int* __restrict__ tile_rowstart,
    const int* __restrict__ total_tiles,
    unsigned short* __restrict__ Yp) {
  int rt = blockIdx.x;
  if (rt >= *total_tiles) return;
  int e = tile_expert[rt];
  int rstart = tile_rowstart[rt];
  int nvalid = offsets[e + 1] - rstart;
  if (nvalid > 128) nvalid = 128;
  int hb = blockIdx.y * 128;
  int koff = blockIdx.z * (FD / 2);
  unsigned short* Ypz = Yp + (size_t)blockIdx.z * NP * HD;

  __shared__ unsigned short Asm[8192];
  __shared__ unsigned short Bsm[8192];

  int tid = threadIdx.x, lane = tid & 63, wv = tid >> 6;
  int qel = ((lane & 7) ^ ((lane >> 3) & 7)) * 8;

  const unsigned short* ag[2];
  const unsigned short* bg[2];
#pragma unroll
  for (int p = 0; p < 2; ++p) {
    int r = p * 64 + wv * 8 + (lane >> 3);
    int rg = rstart + r;
    if (rg > NP - 1) rg = NP - 1;
    ag[p] = Hbuf + (size_t)rg * FD + koff + qel;
    bg[p] = w2c + ((size_t)e * HD + hb + sigma(r)) * FD + koff + qel;
  }

  f32x4 acc[2][4];
  f32x4 vz = {0.f, 0.f, 0.f, 0.f};
#pragma unroll
  for (int i = 0; i < 2; ++i)
#pragma unroll
    for (int j = 0; j < 4; ++j) acc[i][j] = vz;

  int wm = (wv & 3) * 32, wn = (wv >> 2) * 64;
  int lr = lane & 15;

  for (int kb = 0; kb < (FD / 2) / 64; ++kb) {
    __syncthreads();
#pragma unroll
    for (int p = 0; p < 2; ++p) {
      gll16(ag[p], Asm + (p * 512 + wv * 64) * 8);
      gll16(bg[p], Bsm + (p * 512 + wv * 64) * 8);
      ag[p] += 64; bg[p] += 64;
    }
    __syncthreads();
#pragma unroll
    for (int t = 0; t < 2; ++t) {
      int qsl = ((t * 4 + (lane >> 4)) ^ (lr & 7)) * 8;
      bf16x8 af[2], bfr[4];
#pragma unroll
      for (int i = 0; i < 2; ++i) af[i] = frag_ld(&Asm[(wm + i * 16 + lr) * 64 + qsl]);
#pragma unroll
      for (int j = 0; j < 4; ++j) bfr[j] = frag_ld(&Bsm[(wn + j * 16 + lr) * 64 + qsl]);
#pragma unroll
      for (int i = 0; i < 2; ++i)
#pragma unroll
        for (int j = 0; j < 4; ++j)
          acc[i][j] = __builtin_amdgcn_mfma_f32_16x16x32_bf16(af[i], bfr[j], acc[i][j], 0, 0, 0);
    }
  }

  int cb = wn + (lane & 15) * 4;
  int rq = (lane >> 4) * 4;
#pragma unroll
  for (int i = 0; i < 2; ++i) {
#pragma unroll
    for (int r = 0; r < 4; ++r) {
      int row = wm + i * 16 + rq + r;
      if (row < nvalid) {
        int rg = rstart + row;
        float wgt = row_w[rg];
        us4 hv = {f2bf(wgt * acc[i][0][r]), f2bf(wgt * acc[i][1][r]),
                  f2bf(wgt * acc[i][2][r]), f2bf(wgt * acc[i][3][r])};
        nt_store_us4(hv, &Ypz[(size_t)rg * HD + hb + cb]);
      }
    }
  }
}

// combine A: y[s] = sum_k sum_z Yp[z][inv[2s+k]]  (weights pre-applied)
__global__ void combine_a_kernel(const unsigned short* __restrict__ Yp,
                                 const int* __restrict__ inv, float* __restrict__ y) {
  int s = blockIdx.x;
  int c = threadIdx.x * 4;
  f32x4 o = {0.f, 0.f, 0.f, 0.f};
#pragma unroll
  for (int k = 0; k < 2; ++k) {
    int i = inv[s * 2 + k];
#pragma unroll
    for (int z = 0; z < 2; ++z) {
      ushort4 v = *(const ushort4*)(Yp + ((size_t)z * NP + i) * HD + c);
      o.x += bf2f(v.x); o.y += bf2f(v.y); o.z += bf2f(v.z); o.w += bf2f(v.w);
    }
  }
  nt_store_f4(o, y + (size_t)s * HD + c);
}

// ---------------- GEMM2 path B (fallback, r3-proven, 256 thr): fp32 Yp ----------------

__global__ __launch_bounds__(256) void gemm2b_kernel(
    const unsigned short* __restrict__ Hbuf, const unsigned short* __restrict__ w2c,
    const int* __restrict__ offsets,
    const int* __restrict__ tile_expert, const int* __restrict__ tile_rowstart,
    const int* __restrict__ total_tiles,
    float* __restrict__ Yp, int FC, int first) {
  int rt = blockIdx.x;
  if (rt >= *total_tiles) return;
  int e = tile_expert[rt];
  int rstart = tile_rowstart[rt];
  int nvalid = offsets[e + 1] - rstart;
  if (nvalid > 128) nvalid = 128;
  int hb = blockIdx.y * 128;

  __shared__ unsigned short Asm[8192];
  __shared__ unsigned short Bsm[8192];

  int tid = threadIdx.x, lane = tid & 63, wv = tid >> 6;
  int qel = ((lane & 7) ^ ((lane >> 3) & 7)) * 8;

  const unsigned short* ag[4];
  const unsigned short* bg[4];
#pragma unroll
  for (int p = 0; p < 4; ++p) {
    int r = p * 32 + wv * 8 + (lane >> 3);
    int rg = rstart + r;
    if (rg > NP - 1) rg = NP - 1;
    ag[p] = Hbuf + (size_t)rg * FC + qel;
    bg[p] = w2c + ((size_t)e * HD + hb + sigma(r)) * FC + qel;
  }

  f32x4 acc[4][4];
  f32x4 vz = {0.f, 0.f, 0.f, 0.f};
#pragma unroll
  for (int i = 0; i < 4; ++i)
#pragma unroll
    for (int j = 0; j < 4; ++j) acc[i][j] = vz;

  int wm = (wv & 1) * 64, wn = (wv >> 1) * 64;
  int lr = lane & 15;

  for (int kb = 0; kb < FC / 64; ++kb) {
    __syncthreads();
#pragma unroll
    for (int p = 0; p < 4; ++p) {
      gll16(ag[p], Asm + (p * 256 + wv * 64) * 8);
      gll16(bg[p], Bsm + (p * 256 + wv * 64) * 8);
      ag[p] += 64; bg[p] += 64;
    }
    __syncthreads();
#pragma unroll
    for (int t = 0; t < 2; ++t) {
      int qsl = ((t * 4 + (lane >> 4)) ^ (lr & 7)) * 8;
      bf16x8 af[4], bfr[4];
#pragma unroll
      for (int i = 0; i < 4; ++i) af[i] = frag_ld(&Asm[(wm + i * 16 + lr) * 64 + qsl]);
#pragma unroll
      for (int j = 0; j < 4; ++j) bfr[j] = frag_ld(&Bsm[(wn + j * 16 + lr) * 64 + qsl]);
#pragma unroll
      for (int i = 0; i < 4; ++i)
#pragma unroll
        for (int j = 0; j < 4; ++j)
          acc[i][j] = __builtin_amdgcn_mfma_f32_16x16x32_bf16(af[i], bfr[j], acc[i][j], 0, 0, 0);
    }
  }

  int cb = wn + (lane & 15) * 4;
  int rq = (lane >> 4) * 4;
#pragma unroll
  for (int i = 0; i < 4; ++i) {
#pragma unroll
    for (int r = 0; r < 4; ++r) {
      int row = wm + i * 16 + rq + r;
      if (row < nvalid) {
        float* dst = Yp + (size_t)(rstart + row) * HD + hb + cb;
        float4 v;
        v.x = acc[i][0][r]; v.y = acc[i][1][r]; v.z = acc[i][2][r]; v.w = acc[i][3][r];
        if (!first) {
          float4 o = *(const float4*)dst;
          v.x += o.x; v.y += o.y; v.z += o.z; v.w += o.w;
        }
        *(float4*)dst = v;
      }
    }
  }
}

__global__ void combine_b_kernel(const float* __restrict__ Yp, const int* __restrict__ inv,
                                 const float* __restrict__ topk_w, float* __restrict__ y) {
  int s = blockIdx.x;
  int c = threadIdx.x * 4;
  int i0 = inv[s * 2], i1 = inv[s * 2 + 1];
  float w0 = topk_w[s * 2], w1 = topk_w[s * 2 + 1];
  float4 a = *(const float4*)(Yp + (size_t)i0 * HD + c);
  float4 b = *(const float4*)(Yp + (size_t)i1 * HD + c);
  f32x4 o;
  o.x = w0 * a.x + w1 * b.x;
  o.y = w0 * a.y + w1 * b.y;
  o.z = w0 * a.z + w1 * b.z;
  o.w = w0 * a.w + w1 * b.w;
  nt_store_f4(o, y + (size_t)s * HD + c);
}

// ---------------- host ----------------

extern "C" void kernel_launch(void* const* d_in, const int* in_sizes, int n_in,
                              void* d_out, int out_size, void* d_ws, size_t ws_size,
                              hipStream_t stream) {
  const float* x      = (const float*)d_in[0];
  const int*   topk_e = (const int*)d_in[1];
  const float* topk_w = (const float*)d_in[2];
  const float* w1     = (const float*)d_in[3];
  const float* w2     = (const float*)d_in[4];
  float* y = (float*)d_out;

  char* ws = (char*)d_ws;
  int* counts        = (int*)(ws + 0);
  int* cursors       = (int*)(ws + 64);
  int* offsets       = (int*)(ws + 128);
  int* total_tiles   = (int*)(ws + 192);
  int* tile_expert   = (int*)(ws + 256);
  int* tile_rowstart = (int*)(ws + 1024);
  int* row_token     = (int*)(ws + 4096);
  int* inv           = (int*)(ws + 4096 + (size_t)NP * 4);
  float* row_w       = (float*)(ws + 4096 + (size_t)NP * 8);
  size_t hdr = 4096 + (size_t)NP * 12;

  size_t xbytes  = (size_t)SS * HD * 2;            // 16.8 MB
  size_t w1bytes = (size_t)NE * FD * HD * 2;       // 67.1 MB
  size_t hbytes  = (size_t)NP * FD * 2;            // 134.2 MB
  size_t ypAbytes = (size_t)2 * NP * HD * 2;       // 67.1 MB (2 bf16 halves)

  unsigned short* xb = (unsigned short*)(ws + hdr);
  size_t needA = hdr + xbytes + 2 * w1bytes + hbytes + ypAbytes;   // ~352 MB

  hipMemsetAsync(d_ws, 0, 2048, stream);
  count_kernel<<<NP / 256, 256, 0, stream>>>(topk_e, counts);
  plan_kernel<<<1, 1, 0, stream>>>(counts, offsets, cursors, tile_expert, tile_rowstart, total_tiles);
  scatter_kernel<<<NP / 256, 256, 0, stream>>>(topk_e, topk_w, cursors, row_token, inv, row_w);

  if (ws_size >= needA) {
    // ---- Path A: full buffers, LLC-warm ordering, 512-thr GEMMs, bf16 Yp ----
    unsigned short* w1c  = xb + XN;
    unsigned short* w2c  = w1c + W1N;
    unsigned short* Hbuf = w2c + W1N;
    unsigned short* Yp   = Hbuf + (size_t)NP * FD;

    int wblocks = (int)(W1N / 8 / 256);   // 16384
    conv_x_kernel<<<SS * HD / 8 / 256, 256, 0, stream>>>(x, xb);
    conv_w1c_kernel<<<wblocks, 256, 0, stream>>>(w1, w1c, 0, FD);
    gemm1_kernel<<<dim3(MAX_TILES, FD / 128), 512, 0, stream>>>(
        xb, w1c, row_token, offsets, tile_expert, tile_rowstart, total_tiles, Hbuf, FD);
    conv_w2c_kernel<<<wblocks, 256, 0, stream>>>(w2, w2c, 0, FD);
    gemm2a_kernel<<<dim3(MAX_TILES, HD / 128, 2), 512, 0, stream>>>(
        Hbuf, w2c, row_w, offsets, tile_expert, tile_rowstart, total_tiles, Yp);
    combine_a_kernel<<<SS, 256, 0, stream>>>(Yp, inv, y);
  } else {
    // ---- Path B: chunked fallback (shared weight scratch, fp32 Yp) ----
    size_t ypbytes = (size_t)NP * HD * 4;
    int FC = FD;
    while (FC > 256) {
      size_t need = hdr + xbytes + (size_t)NE * FC * HD * 2 + (size_t)NP * FC * 2 + ypbytes;
      if (need <= ws_size) break;
      FC >>= 1;
    }
    unsigned short* wc = xb + XN;
    unsigned short* Hbuf = wc + (size_t)NE * FC * HD;
    float* Yp = (float*)(Hbuf + (size_t)NP * FC);

    conv_x_kernel<<<SS * HD / 8 / 256, 256, 0, stream>>>(x, xb);
    int nchunks = FD / FC;
    int wblocks = (int)((size_t)NE * FC * HD / 8 / 256);
    for (int c = 0; c < nchunks; ++c) {
      conv_w1c_kernel<<<wblocks, 256, 0, stream>>>(w1, wc, c, FC);
      gemm1_kernel<<<dim3(MAX_TILES, FC / 128), 512, 0, stream>>>(
          xb, wc, row_token, offsets, tile_expert, tile_rowstart, total_tiles, Hbuf, FC);
      conv_w2c_kernel<<<wblocks, 256, 0, stream>>>(w2, wc, c, FC);
      gemm2b_kernel<<<dim3(MAX_TILES, HD / 128), 256, 0, stream>>>(
          Hbuf, wc, offsets, tile_expert, tile_rowstart, total_tiles, Yp, FC, c == 0 ? 1 : 0);
    }
    combine_b_kernel<<<SS, 256, 0, stream>>>(Yp, inv, topk_w, y);
  }
}